// Round 16
// baseline (158.446 us; speedup 1.0000x reference)
//
#include <hip/hip_runtime.h>
#include <math.h>

#define NPTS 200000
#define NHALF 100000
#define KNBR 16
#define CDIM 32
#define NITEM (NPTS * KNBR)               // 3,200,000
#define TEMP 0.1f
#define WEIGHT 0.1f
#define EPSV 1e-8f

#define BLD_BLOCKS ((NPTS + 255) / 256)   // 782
#define PD_BLOCKS 1568                    // 784 blocks per group
#define PD_STRIDE 6272                    // 784 blocks * 8 points/block/iter
#define CMB_BLOCKS ((NPTS + 255) / 256)   // 782

// 4-bit linear quant for dims 30,31: x_hat = (q-7)*QS, q in 0..14
#define QS 0.55f

// ---- workspace layout (byte offsets) ----
// Unified table: 32B/point (0-15: dims0-15 fp8; 16-29: dims16-29 fp8;
// byte30: q4(d30)|q4(d31)<<4; byte31: label).
// PG: per-group partial softmax, float4 {min_d, pos_sum, neg_sum, cnt},
// PG[g*NPTS + p].
#define TBL_OFF  4096
#define PG_OFF   (TBL_OFF + NPTS * 32)            // +6.4MB
#define BL_OFF   (PG_OFF + (size_t)2 * NPTS * 16) // +6.4MB
#define BC_OFF   (BL_OFF + CMB_BLOCKS * 4)
#define WS_NEEDED ((size_t)(BC_OFF + CMB_BLOCKS * 4))

typedef float v2f __attribute__((ext_vector_type(2)));
typedef float v4f __attribute__((ext_vector_type(4)));
typedef int   v4i __attribute__((ext_vector_type(4)));
typedef unsigned v4u __attribute__((ext_vector_type(4)));

static __device__ __forceinline__ int q4(float x) {
    int q = (int)rintf(x * (1.0f / QS)) + 7;
    return q < 0 ? 0 : (q > 14 ? 14 : q);
}

// ---------- K1: one thread per point -> one 32B row ------------------------
__global__ __launch_bounds__(256) void build_table(
    const float* __restrict__ f, const int* __restrict__ labels,
    unsigned char* __restrict__ T) {
    const int p = blockIdx.x * 256 + threadIdx.x;
    if (p >= NPTS) return;
    const v4f* fp = (const v4f*)(f + (size_t)p * CDIM);
    const v4f v0 = __builtin_nontemporal_load(fp + 0);
    const v4f v1 = __builtin_nontemporal_load(fp + 1);
    const v4f v2 = __builtin_nontemporal_load(fp + 2);
    const v4f v3 = __builtin_nontemporal_load(fp + 3);
    const v4f v4 = __builtin_nontemporal_load(fp + 4);
    const v4f v5 = __builtin_nontemporal_load(fp + 5);
    const v4f v6 = __builtin_nontemporal_load(fp + 6);
    const v4f v7 = __builtin_nontemporal_load(fp + 7);

    int a0 = 0, a1 = 0, a2 = 0, a3 = 0;
    a0 = __builtin_amdgcn_cvt_pk_fp8_f32(v0.x, v0.y, a0, false);
    a0 = __builtin_amdgcn_cvt_pk_fp8_f32(v0.z, v0.w, a0, true);
    a1 = __builtin_amdgcn_cvt_pk_fp8_f32(v1.x, v1.y, a1, false);
    a1 = __builtin_amdgcn_cvt_pk_fp8_f32(v1.z, v1.w, a1, true);
    a2 = __builtin_amdgcn_cvt_pk_fp8_f32(v2.x, v2.y, a2, false);
    a2 = __builtin_amdgcn_cvt_pk_fp8_f32(v2.z, v2.w, a2, true);
    a3 = __builtin_amdgcn_cvt_pk_fp8_f32(v3.x, v3.y, a3, false);
    a3 = __builtin_amdgcn_cvt_pk_fp8_f32(v3.z, v3.w, a3, true);
    v4u ra; ra.x = (unsigned)a0; ra.y = (unsigned)a1;
    ra.z = (unsigned)a2; ra.w = (unsigned)a3;

    int b0 = 0, b1 = 0, b2 = 0, b3 = 0;
    b0 = __builtin_amdgcn_cvt_pk_fp8_f32(v4.x, v4.y, b0, false);
    b0 = __builtin_amdgcn_cvt_pk_fp8_f32(v4.z, v4.w, b0, true);
    b1 = __builtin_amdgcn_cvt_pk_fp8_f32(v5.x, v5.y, b1, false);
    b1 = __builtin_amdgcn_cvt_pk_fp8_f32(v5.z, v5.w, b1, true);
    b2 = __builtin_amdgcn_cvt_pk_fp8_f32(v6.x, v6.y, b2, false);
    b2 = __builtin_amdgcn_cvt_pk_fp8_f32(v6.z, v6.w, b2, true);
    b3 = __builtin_amdgcn_cvt_pk_fp8_f32(v7.x, v7.y, b3, false);  // dims 28,29
    const int pk = q4(v7.z) | (q4(v7.w) << 4);                    // dims 30,31
    b3 = (b3 & 0xffff) | (pk << 16) | ((labels[p] & 0xff) << 24);
    v4u rb; rb.x = (unsigned)b0; rb.y = (unsigned)b1;
    rb.z = (unsigned)b2; rb.w = (unsigned)b3;

    v4u* dst = (v4u*)(T + (size_t)p * 32);
    __builtin_nontemporal_store(ra, dst);
    __builtin_nontemporal_store(rb, dst + 1);
}

// ---------- K2: lane-pair gather + in-register group-partial softmax -------
// 2 lanes per item (even: row bytes 0-15, odd: bytes 16-31) -> the wave's
// single gather instruction coalesces each pair into ONE 32B segment
// (intra-instruction merge), halving line-requests vs 2-instruction rows.
// 32 lanes = one point (16 items); wave = 2 points. nbr-range split keeps
// each group's 3.2MB table half L2-resident; loads branch-skipped so only
// owned requests issue (R13 lesson). Partial softmax in-register, one
// float4 store per point per group (R14-verified combine semantics).
__global__ __launch_bounds__(256) void pd2_pair(
    const unsigned char* __restrict__ T,
    const int* __restrict__ nbr,
    float4* __restrict__ PG) {
    const int b = blockIdx.x;
    const int g = ((b & 7) < 4) ? 0 : 1;
    const int r = (b >> 3) * 4 + (b & 3);          // 0..783 within group
    const int tid = threadIdx.x;
    const int w = tid >> 6;                        // wave 0..3
    const int l = tid & 63;
    const int half = l & 1;                        // 16B half of the row
    const int item = (l & 31) >> 1;                // 0..15
    const int sub = l >> 5;                        // point within wave

    for (int p = r * 8 + w * 2 + sub; p < NPTS; p += PD_STRIDE) {
        const int id = nbr[(size_t)p * KNBR + item];     // pair-broadcast
        const bool own = g ? (id >= NHALF) : (id < NHALF);

        // center half-row: 2 distinct 16B per 32-lane group (broadcast)
        const v4u cv = *(const v4u*)(T + (size_t)p * 32 + (size_t)half * 16);

        v4u nv; nv.x = 0u; nv.y = 0u; nv.z = 0u; nv.w = 0u;
        if (own)                                   // only owned requests issue
            nv = *(const v4u*)(T + (size_t)id * 32 + (size_t)half * 16);

        float d2 = 0.f;
        float posflag = 0.f;
        if (own) {
            #pragma unroll
            for (int q = 0; q < 3; ++q) {          // 12 fp8 dims
                v2f cl = __builtin_amdgcn_cvt_pk_f32_fp8((int)cv[q], false);
                v2f ch = __builtin_amdgcn_cvt_pk_f32_fp8((int)cv[q], true);
                v2f nl = __builtin_amdgcn_cvt_pk_f32_fp8((int)nv[q], false);
                v2f nh = __builtin_amdgcn_cvt_pk_f32_fp8((int)nv[q], true);
                float a0 = cl.x - nl.x, a1 = cl.y - nl.y;
                float a2 = ch.x - nh.x, a3 = ch.y - nh.y;
                d2 += a0 * a0 + a1 * a1 + a2 * a2 + a3 * a3;
            }
            {   // low pair of dword3: fp8 dims in both halves
                v2f cl = __builtin_amdgcn_cvt_pk_f32_fp8((int)cv[3], false);
                v2f nl = __builtin_amdgcn_cvt_pk_f32_fp8((int)nv[3], false);
                float a0 = cl.x - nl.x, a1 = cl.y - nl.y;
                d2 += a0 * a0 + a1 * a1;
            }
            if (half == 0) {                       // dims 14,15 fp8
                v2f ch = __builtin_amdgcn_cvt_pk_f32_fp8((int)cv[3], true);
                v2f nh = __builtin_amdgcn_cvt_pk_f32_fp8((int)nv[3], true);
                float a0 = ch.x - nh.x, a1 = ch.y - nh.y;
                d2 += a0 * a0 + a1 * a1;
            } else {                               // q4 dims 30,31 + label
                const unsigned cb = (cv[3] >> 16) & 0xffu;
                const unsigned nb2 = (nv[3] >> 16) & 0xffu;
                const float a0 = ((float)(cb & 15u) - (float)(nb2 & 15u)) * QS;
                const float a1 = ((float)(cb >> 4) - (float)(nb2 >> 4)) * QS;
                d2 += a0 * a0 + a1 * a1;
                posflag = ((nv[3] >> 24) == (cv[3] >> 24)) ? 1.f : 0.f;
            }
        }
        // pair combine: full d^2 and pos flag on both lanes
        d2 += __shfl_xor(d2, 1);
        posflag += __shfl_xor(posflag, 1);
        const float d = own ? sqrtf(d2 + EPSV) : INFINITY;

        // group-local (16-item) partial softmax over the 32-lane group
        float mn = d;
        #pragma unroll
        for (int off = 2; off <= 16; off <<= 1)
            mn = fminf(mn, __shfl_xor(mn, off));

        float e = 0.f, pe = 0.f, ct = 0.f;
        if (own && half == 0) {                    // one contribution per item
            e = expf((mn - d) * (1.0f / TEMP));
            if (posflag > 0.5f) { pe = e; ct = 1.f; }
        }
        #pragma unroll
        for (int off = 2; off <= 16; off <<= 1) {
            e += __shfl_xor(e, off);
            pe += __shfl_xor(pe, off);
            ct += __shfl_xor(ct, off);
        }
        if ((l & 31) == 0) {
            float4 outv; outv.x = mn; outv.y = pe; outv.z = e; outv.w = ct;
            PG[(size_t)g * NPTS + p] = outv;       // coalesced-ish 16B store
        }
    }
}

// ---------- K3: combine two group partials + per-point loss + block reduce -
__global__ __launch_bounds__(256) void combine_loss(
    const float4* __restrict__ PG,
    float* __restrict__ bl, float* __restrict__ bc) {
    const int tid = threadIdx.x;
    const int p = blockIdx.x * 256 + tid;
    float loss = 0.f, valid = 0.f;
    if (p < NPTS) {
        const float4 a = PG[p];
        const float4 b = PG[(size_t)NPTS + p];
        const float m = fminf(a.x, b.x);
        const float s0 = expf((m - a.x) * (1.0f / TEMP));   // 0 if a.x=INF
        const float s1 = expf((m - b.x) * (1.0f / TEMP));
        const float pos = a.y * s0 + b.y * s1;
        const float neg = a.z * s0 + b.z * s1;
        const int cnt = (int)(a.w + b.w + 0.5f);
        if (cnt > 0 && cnt < KNBR) {
            loss = -logf(pos / neg + EPSV);
            valid = 1.f;
        }
    }
    #pragma unroll
    for (int off = 1; off <= 32; off <<= 1) {
        loss += __shfl_xor(loss, off);
        valid += __shfl_xor(valid, off);
    }
    __shared__ float sl[4], sv[4];
    if ((tid & 63) == 0) { sl[tid >> 6] = loss; sv[tid >> 6] = valid; }
    __syncthreads();
    if (tid == 0) {
        bl[blockIdx.x] = sl[0] + sl[1] + sl[2] + sl[3];   // plain store
        bc[blockIdx.x] = sv[0] + sv[1] + sv[2] + sv[3];
    }
}

// ---------- K4: single-block final reduction -------------------------------
__global__ __launch_bounds__(256) void final_reduce(const float* __restrict__ bl,
                                                    const float* __restrict__ bc,
                                                    float* __restrict__ out) {
    const int tid = threadIdx.x;
    float l = 0.f, v = 0.f;
    for (int i = tid; i < CMB_BLOCKS; i += 256) { l += bl[i]; v += bc[i]; }
    #pragma unroll
    for (int off = 1; off <= 32; off <<= 1) {
        l += __shfl_xor(l, off);
        v += __shfl_xor(v, off);
    }
    __shared__ float sl[4], sv[4];
    if ((tid & 63) == 0) { sl[tid >> 6] = l; sv[tid >> 6] = v; }
    __syncthreads();
    if (tid == 0) {
        const float S = sl[0] + sl[1] + sl[2] + sl[3];
        const float C = sv[0] + sv[1] + sv[2] + sv[3];
        out[0] = S / fmaxf(C, 1.f) * WEIGHT;
    }
}

// ---------------- fp32 direct fallback (tiny ws) ---------------------------
__global__ __launch_bounds__(256) void contrast_fp32(
    const float* __restrict__ features,
    const int* __restrict__ labels,
    const int* __restrict__ nbr,
    float* __restrict__ ws) {
    const int lane = threadIdx.x & 63;
    const int wave = threadIdx.x >> 6;
    const int p0 = blockIdx.x * 16 + wave * 4;
    const int m = lane >> 3;
    const int c = lane & 7;
    const int idx_l = nbr[p0 * KNBR + lane];
    const int labn_l = labels[idx_l];
    const int labc_l = labels[p0 + (lane >> 4)];
    float4 cen[4];
    #pragma unroll
    for (int pt = 0; pt < 4; ++pt)
        cen[pt] = *(const float4*)(features + (size_t)(p0 + pt) * CDIM + c * 4);
    int ridx[8];
    #pragma unroll
    for (int j = 0; j < 8; ++j) ridx[j] = __shfl(idx_l, 8 * j + m);
    float4 v[8];
    #pragma unroll
    for (int j = 0; j < 8; ++j)
        v[j] = *(const float4*)(features + (size_t)ridx[j] * CDIM + c * 4);
    float dj[8];
    #pragma unroll
    for (int j = 0; j < 8; ++j) {
        float4 ce = cen[j >> 1];
        float dx = ce.x - v[j].x, dy = ce.y - v[j].y;
        float dz = ce.z - v[j].z, dw = ce.w - v[j].w;
        float d2 = dx * dx + dy * dy + dz * dz + dw * dw;
        d2 += __shfl_xor(d2, 1);
        d2 += __shfl_xor(d2, 2);
        d2 += __shfl_xor(d2, 4);
        dj[j] = sqrtf(d2 + EPSV);
    }
    float loss_acc = 0.f, valid_acc = 0.f;
    #pragma unroll
    for (int pt = 0; pt < 4; ++pt) {
        float a = dj[2 * pt], b = dj[2 * pt + 1];
        float mn = fminf(a, b);
        mn = fminf(mn, __shfl_xor(mn, 8));
        mn = fminf(mn, __shfl_xor(mn, 16));
        mn = fminf(mn, __shfl_xor(mn, 32));
        const float ea = expf((mn - a) / TEMP);
        const float eb = expf((mn - b) / TEMP);
        const int la = __shfl(labn_l, 16 * pt + m);
        const int lb = __shfl(labn_l, 16 * pt + 8 + m);
        const int lc = __shfl(labc_l, 16 * pt);
        float pos_s = (la == lc ? ea : 0.f) + (lb == lc ? eb : 0.f);
        float neg_s = ea + eb;
        float cnt_s = (la == lc ? 1.f : 0.f) + (lb == lc ? 1.f : 0.f);
        #pragma unroll
        for (int off = 8; off <= 32; off <<= 1) {
            pos_s += __shfl_xor(pos_s, off);
            neg_s += __shfl_xor(neg_s, off);
            cnt_s += __shfl_xor(cnt_s, off);
        }
        if (lane == pt) {
            const int icnt = (int)(cnt_s + 0.5f);
            if (icnt > 0 && icnt < KNBR) {
                loss_acc += -logf(pos_s / neg_s + EPSV);
                valid_acc += 1.f;
            }
        }
    }
    __shared__ float s_loss, s_cnt;
    if (threadIdx.x == 0) { s_loss = 0.f; s_cnt = 0.f; }
    __syncthreads();
    if (lane < 4) { atomicAdd(&s_loss, loss_acc); atomicAdd(&s_cnt, valid_acc); }
    __syncthreads();
    if (threadIdx.x == 0) { atomicAdd(&ws[0], s_loss); atomicAdd(&ws[1], s_cnt); }
}

__global__ void contrast_finalize(const float* __restrict__ ws,
                                  float* __restrict__ out) {
    out[0] = ws[0] / fmaxf(ws[1], 1.f) * WEIGHT;
}

extern "C" void kernel_launch(void* const* d_in, const int* in_sizes, int n_in,
                              void* d_out, int out_size, void* d_ws, size_t ws_size,
                              hipStream_t stream) {
    const float* features = (const float*)d_in[0];
    const int* labels     = (const int*)d_in[1];
    const int* nbr        = (const int*)d_in[2];
    float* out = (float*)d_out;
    float* ws  = (float*)d_ws;

    if (ws_size >= WS_NEEDED) {
        unsigned char* tbl = (unsigned char*)d_ws + TBL_OFF;
        float4* PG = (float4*)((char*)d_ws + PG_OFF);
        float* bl = (float*)((char*)d_ws + BL_OFF);
        float* bc = (float*)((char*)d_ws + BC_OFF);

        build_table<<<BLD_BLOCKS, 256, 0, stream>>>(features, labels, tbl);
        pd2_pair<<<PD_BLOCKS, 256, 0, stream>>>(tbl, nbr, PG);
        combine_loss<<<CMB_BLOCKS, 256, 0, stream>>>(PG, bl, bc);
        final_reduce<<<1, 256, 0, stream>>>(bl, bc, out);
    } else {
        (void)hipMemsetAsync(ws, 0, 16, stream);
        contrast_fp32<<<NPTS / 16, 256, 0, stream>>>(features, labels, nbr, ws);
        contrast_finalize<<<1, 1, 0, stream>>>(ws, out);
    }
}

// Round 17
// 127.574 us; speedup vs baseline: 1.2420x; 1.2420x over previous
//
#include <hip/hip_runtime.h>
#include <math.h>

#define NPTS 200000
#define NHALF 100000
#define KNBR 16
#define CDIM 32
#define NITEM (NPTS * KNBR)               // 3,200,000
#define TEMP 0.1f
#define WEIGHT 0.1f
#define EPSV 1e-8f

#define BLD_BLOCKS ((NPTS + 255) / 256)   // 782
#define PD_BLOCKS 2496                    // 1248 blocks per nbr-range group
#define PD_RANKS 3125                     // rank = 1024 items
#define PD_GSTRIDE 1248
#define CMB_BLOCKS ((NPTS + 255) / 256)   // 782

// 4-bit linear quant for dims 30,31: x_hat = (q-7)*QS, q in 0..14
#define QS 0.55f

// ---- workspace layout (byte offsets) ----
// Unified table: 32B/point (0-15: dims0-15 fp8; 16-29: dims16-29 fp8;
// byte30: q4(d30)|q4(d31)<<4; byte31: label).
// PG: per-group partial softmax, float4 {min_d, pos_sum, neg_sum, cnt},
// PG[g*NPTS + p].
#define TBL_OFF  4096
#define PG_OFF   (TBL_OFF + NPTS * 32)            // +6.4MB
#define BL_OFF   (PG_OFF + (size_t)2 * NPTS * 16) // +6.4MB
#define BC_OFF   (BL_OFF + CMB_BLOCKS * 4)
#define WS_NEEDED ((size_t)(BC_OFF + CMB_BLOCKS * 4))

typedef float v2f __attribute__((ext_vector_type(2)));
typedef float v4f __attribute__((ext_vector_type(4)));
typedef int   v4i __attribute__((ext_vector_type(4)));
typedef unsigned v4u __attribute__((ext_vector_type(4)));

static __device__ __forceinline__ int q4(float x) {
    int q = (int)rintf(x * (1.0f / QS)) + 7;
    return q < 0 ? 0 : (q > 14 ? 14 : q);
}

// ---------- K1: one thread per point -> one 32B row ------------------------
__global__ __launch_bounds__(256) void build_table(
    const float* __restrict__ f, const int* __restrict__ labels,
    unsigned char* __restrict__ T) {
    const int p = blockIdx.x * 256 + threadIdx.x;
    if (p >= NPTS) return;
    const v4f* fp = (const v4f*)(f + (size_t)p * CDIM);
    const v4f v0 = __builtin_nontemporal_load(fp + 0);
    const v4f v1 = __builtin_nontemporal_load(fp + 1);
    const v4f v2 = __builtin_nontemporal_load(fp + 2);
    const v4f v3 = __builtin_nontemporal_load(fp + 3);
    const v4f v4 = __builtin_nontemporal_load(fp + 4);
    const v4f v5 = __builtin_nontemporal_load(fp + 5);
    const v4f v6 = __builtin_nontemporal_load(fp + 6);
    const v4f v7 = __builtin_nontemporal_load(fp + 7);

    int a0 = 0, a1 = 0, a2 = 0, a3 = 0;
    a0 = __builtin_amdgcn_cvt_pk_fp8_f32(v0.x, v0.y, a0, false);
    a0 = __builtin_amdgcn_cvt_pk_fp8_f32(v0.z, v0.w, a0, true);
    a1 = __builtin_amdgcn_cvt_pk_fp8_f32(v1.x, v1.y, a1, false);
    a1 = __builtin_amdgcn_cvt_pk_fp8_f32(v1.z, v1.w, a1, true);
    a2 = __builtin_amdgcn_cvt_pk_fp8_f32(v2.x, v2.y, a2, false);
    a2 = __builtin_amdgcn_cvt_pk_fp8_f32(v2.z, v2.w, a2, true);
    a3 = __builtin_amdgcn_cvt_pk_fp8_f32(v3.x, v3.y, a3, false);
    a3 = __builtin_amdgcn_cvt_pk_fp8_f32(v3.z, v3.w, a3, true);
    v4u ra; ra.x = (unsigned)a0; ra.y = (unsigned)a1;
    ra.z = (unsigned)a2; ra.w = (unsigned)a3;

    int b0 = 0, b1 = 0, b2 = 0, b3 = 0;
    b0 = __builtin_amdgcn_cvt_pk_fp8_f32(v4.x, v4.y, b0, false);
    b0 = __builtin_amdgcn_cvt_pk_fp8_f32(v4.z, v4.w, b0, true);
    b1 = __builtin_amdgcn_cvt_pk_fp8_f32(v5.x, v5.y, b1, false);
    b1 = __builtin_amdgcn_cvt_pk_fp8_f32(v5.z, v5.w, b1, true);
    b2 = __builtin_amdgcn_cvt_pk_fp8_f32(v6.x, v6.y, b2, false);
    b2 = __builtin_amdgcn_cvt_pk_fp8_f32(v6.z, v6.w, b2, true);
    b3 = __builtin_amdgcn_cvt_pk_fp8_f32(v7.x, v7.y, b3, false);  // dims 28,29
    const int pk = q4(v7.z) | (q4(v7.w) << 4);                    // dims 30,31
    b3 = (b3 & 0xffff) | (pk << 16) | ((labels[p] & 0xff) << 24);
    v4u rb; rb.x = (unsigned)b0; rb.y = (unsigned)b1;
    rb.z = (unsigned)b2; rb.w = (unsigned)b3;

    v4u* dst = (v4u*)(T + (size_t)p * 32);
    __builtin_nontemporal_store(ra, dst);
    __builtin_nontemporal_store(rb, dst + 1);
}

// ---------- K2: R12 gather (verbatim structure) + fused partial softmax ----
// 4 items/thread, 4 consecutive lanes = 1 point. nbr-range split: group 0
// (XCDs 0-3) owns id<NHALF (rows 0..NHALF-1 = 3.2MB L2-set), group 1 the
// rest. Neighbor loads branch-skipped (R13 lesson: only owned requests
// issue). NEW vs R12: instead of writing d2 halves, compute the group's
// partial softmax {min, pos, neg, cnt} in-register (2-level shuffle over
// the 4-lane point group, R14-verified combine semantics) and store ONE
// float4 per point per group. softmax_point kernel eliminated.
__global__ __launch_bounds__(256) void pd2_pg(
    const unsigned char* __restrict__ T,
    const int* __restrict__ nbr,
    float4* __restrict__ PG) {
    const int b = blockIdx.x;
    const int g = ((b & 7) < 4) ? 0 : 1;
    const int r = (b >> 3) * 4 + (b & 3);          // 0..1247 within group
    const int tid = threadIdx.x;
    const int l = tid & 63;
    float4* __restrict__ pgdst = PG + (size_t)g * NPTS;

    for (int rr = r; rr < PD_RANKS; rr += PD_GSTRIDE) {
        const int i = rr * 1024 + tid * 4;         // 4 items, same center
        const v4i idx4 = __builtin_nontemporal_load((const v4i*)(nbr + i));
        const int p = i >> 4;

        int ids[4];
        ids[0] = idx4.x; ids[1] = idx4.y; ids[2] = idx4.z; ids[3] = idx4.w;
        bool own[4];
        #pragma unroll
        for (int k = 0; k < 4; ++k)
            own[k] = g ? (ids[k] >= NHALF) : (ids[k] < NHALF);

        const v4u* crow = (const v4u*)(T + (size_t)p * 32);
        const v4u cv0 = __builtin_nontemporal_load(crow);
        const v4u cv1 = __builtin_nontemporal_load(crow + 1);

        // decode center once: 30 fp8 pairs + 2 q4 + label
        v2f c[15];
        #pragma unroll
        for (int q = 0; q < 4; ++q) {
            c[2 * q]     = __builtin_amdgcn_cvt_pk_f32_fp8((int)cv0[q], false);
            c[2 * q + 1] = __builtin_amdgcn_cvt_pk_f32_fp8((int)cv0[q], true);
        }
        #pragma unroll
        for (int q = 0; q < 3; ++q) {
            c[8 + 2 * q]     = __builtin_amdgcn_cvt_pk_f32_fp8((int)cv1[q], false);
            c[8 + 2 * q + 1] = __builtin_amdgcn_cvt_pk_f32_fp8((int)cv1[q], true);
        }
        c[14] = __builtin_amdgcn_cvt_pk_f32_fp8((int)cv1[3], false);  // 28,29
        const unsigned cb = (cv1[3] >> 16) & 0xffu;
        const float c30 = (float)(cb & 15u) * QS - 7.0f * QS;
        const float c31 = (float)(cb >> 4) * QS - 7.0f * QS;
        const unsigned clab = cv1[3] >> 24;

        float d[4];
        unsigned posm = 0;
        #pragma unroll
        for (int k = 0; k < 4; ++k) {
            float dv = INFINITY;
            if (own[k]) {                          // only owned requests issue
                const v4u* nrow = (const v4u*)(T + (size_t)ids[k] * 32);
                const v4u nv0 = nrow[0];
                const v4u nv1 = nrow[1];
                float d2 = 0.f;
                #pragma unroll
                for (int q = 0; q < 4; ++q) {      // dims 0-15
                    v2f nl = __builtin_amdgcn_cvt_pk_f32_fp8((int)nv0[q], false);
                    v2f nh = __builtin_amdgcn_cvt_pk_f32_fp8((int)nv0[q], true);
                    float a0 = c[2 * q].x - nl.x, a1 = c[2 * q].y - nl.y;
                    float a2 = c[2 * q + 1].x - nh.x, a3 = c[2 * q + 1].y - nh.y;
                    d2 += a0 * a0 + a1 * a1 + a2 * a2 + a3 * a3;
                }
                #pragma unroll
                for (int q = 0; q < 3; ++q) {      // dims 16-27
                    v2f nl = __builtin_amdgcn_cvt_pk_f32_fp8((int)nv1[q], false);
                    v2f nh = __builtin_amdgcn_cvt_pk_f32_fp8((int)nv1[q], true);
                    float a0 = c[8 + 2 * q].x - nl.x, a1 = c[8 + 2 * q].y - nl.y;
                    float a2 = c[8 + 2 * q + 1].x - nh.x, a3 = c[8 + 2 * q + 1].y - nh.y;
                    d2 += a0 * a0 + a1 * a1 + a2 * a2 + a3 * a3;
                }
                {   // dims 28,29
                    v2f nl = __builtin_amdgcn_cvt_pk_f32_fp8((int)nv1[3], false);
                    float a0 = c[14].x - nl.x, a1 = c[14].y - nl.y;
                    d2 += a0 * a0 + a1 * a1;
                }
                {   // dims 30,31 (q4 codes in byte 30)
                    const unsigned nb = (nv1[3] >> 16) & 0xffu;
                    const float n30 = (float)(nb & 15u) * QS - 7.0f * QS;
                    const float n31 = (float)(nb >> 4) * QS - 7.0f * QS;
                    const float a0 = c30 - n30, a1 = c31 - n31;
                    d2 += a0 * a0 + a1 * a1;
                }
                dv = sqrtf(d2 + EPSV);
                if ((nv1[3] >> 24) == clab) posm |= (1u << k);
            }
            d[k] = dv;
        }

        // group-partial softmax over this point's 16 items (4 lanes x 4)
        float mn = fminf(fminf(d[0], d[1]), fminf(d[2], d[3]));
        mn = fminf(mn, __shfl_xor(mn, 1));
        mn = fminf(mn, __shfl_xor(mn, 2));         // min over owned (INF else)

        float e = 0.f, pe = 0.f, ct = 0.f;
        #pragma unroll
        for (int k = 0; k < 4; ++k) {
            if (d[k] < 3.0e37f) {
                const float ex = expf((mn - d[k]) * (1.0f / TEMP));
                e += ex;
                if (posm & (1u << k)) { pe += ex; ct += 1.f; }
            }
        }
        #pragma unroll
        for (int off = 1; off <= 2; off <<= 1) {
            e += __shfl_xor(e, off);
            pe += __shfl_xor(pe, off);
            ct += __shfl_xor(ct, off);
        }
        if ((l & 3) == 0) {                        // coalesced 16B/point
            float4 outv; outv.x = mn; outv.y = pe; outv.z = e; outv.w = ct;
            pgdst[p] = outv;
        }
    }
}

// ---------- K3: combine two group partials + per-point loss + block reduce -
__global__ __launch_bounds__(256) void combine_loss(
    const float4* __restrict__ PG,
    float* __restrict__ bl, float* __restrict__ bc) {
    const int tid = threadIdx.x;
    const int p = blockIdx.x * 256 + tid;
    float loss = 0.f, valid = 0.f;
    if (p < NPTS) {
        const float4 a = PG[p];
        const float4 b = PG[(size_t)NPTS + p];
        const float m = fminf(a.x, b.x);
        const float s0 = expf((m - a.x) * (1.0f / TEMP));   // 0 if a.x=INF
        const float s1 = expf((m - b.x) * (1.0f / TEMP));
        const float pos = a.y * s0 + b.y * s1;
        const float neg = a.z * s0 + b.z * s1;
        const int cnt = (int)(a.w + b.w + 0.5f);
        if (cnt > 0 && cnt < KNBR) {
            loss = -logf(pos / neg + EPSV);
            valid = 1.f;
        }
    }
    #pragma unroll
    for (int off = 1; off <= 32; off <<= 1) {
        loss += __shfl_xor(loss, off);
        valid += __shfl_xor(valid, off);
    }
    __shared__ float sl[4], sv[4];
    if ((tid & 63) == 0) { sl[tid >> 6] = loss; sv[tid >> 6] = valid; }
    __syncthreads();
    if (tid == 0) {
        bl[blockIdx.x] = sl[0] + sl[1] + sl[2] + sl[3];   // plain store
        bc[blockIdx.x] = sv[0] + sv[1] + sv[2] + sv[3];
    }
}

// ---------- K4: single-block final reduction -------------------------------
__global__ __launch_bounds__(256) void final_reduce(const float* __restrict__ bl,
                                                    const float* __restrict__ bc,
                                                    float* __restrict__ out) {
    const int tid = threadIdx.x;
    float l = 0.f, v = 0.f;
    for (int i = tid; i < CMB_BLOCKS; i += 256) { l += bl[i]; v += bc[i]; }
    #pragma unroll
    for (int off = 1; off <= 32; off <<= 1) {
        l += __shfl_xor(l, off);
        v += __shfl_xor(v, off);
    }
    __shared__ float sl[4], sv[4];
    if ((tid & 63) == 0) { sl[tid >> 6] = l; sv[tid >> 6] = v; }
    __syncthreads();
    if (tid == 0) {
        const float S = sl[0] + sl[1] + sl[2] + sl[3];
        const float C = sv[0] + sv[1] + sv[2] + sv[3];
        out[0] = S / fmaxf(C, 1.f) * WEIGHT;
    }
}

// ---------------- fp32 direct fallback (tiny ws) ---------------------------
__global__ __launch_bounds__(256) void contrast_fp32(
    const float* __restrict__ features,
    const int* __restrict__ labels,
    const int* __restrict__ nbr,
    float* __restrict__ ws) {
    const int lane = threadIdx.x & 63;
    const int wave = threadIdx.x >> 6;
    const int p0 = blockIdx.x * 16 + wave * 4;
    const int m = lane >> 3;
    const int c = lane & 7;
    const int idx_l = nbr[p0 * KNBR + lane];
    const int labn_l = labels[idx_l];
    const int labc_l = labels[p0 + (lane >> 4)];
    float4 cen[4];
    #pragma unroll
    for (int pt = 0; pt < 4; ++pt)
        cen[pt] = *(const float4*)(features + (size_t)(p0 + pt) * CDIM + c * 4);
    int ridx[8];
    #pragma unroll
    for (int j = 0; j < 8; ++j) ridx[j] = __shfl(idx_l, 8 * j + m);
    float4 v[8];
    #pragma unroll
    for (int j = 0; j < 8; ++j)
        v[j] = *(const float4*)(features + (size_t)ridx[j] * CDIM + c * 4);
    float dj[8];
    #pragma unroll
    for (int j = 0; j < 8; ++j) {
        float4 ce = cen[j >> 1];
        float dx = ce.x - v[j].x, dy = ce.y - v[j].y;
        float dz = ce.z - v[j].z, dw = ce.w - v[j].w;
        float d2 = dx * dx + dy * dy + dz * dz + dw * dw;
        d2 += __shfl_xor(d2, 1);
        d2 += __shfl_xor(d2, 2);
        d2 += __shfl_xor(d2, 4);
        dj[j] = sqrtf(d2 + EPSV);
    }
    float loss_acc = 0.f, valid_acc = 0.f;
    #pragma unroll
    for (int pt = 0; pt < 4; ++pt) {
        float a = dj[2 * pt], b = dj[2 * pt + 1];
        float mn = fminf(a, b);
        mn = fminf(mn, __shfl_xor(mn, 8));
        mn = fminf(mn, __shfl_xor(mn, 16));
        mn = fminf(mn, __shfl_xor(mn, 32));
        const float ea = expf((mn - a) / TEMP);
        const float eb = expf((mn - b) / TEMP);
        const int la = __shfl(labn_l, 16 * pt + m);
        const int lb = __shfl(labn_l, 16 * pt + 8 + m);
        const int lc = __shfl(labc_l, 16 * pt);
        float pos_s = (la == lc ? ea : 0.f) + (lb == lc ? eb : 0.f);
        float neg_s = ea + eb;
        float cnt_s = (la == lc ? 1.f : 0.f) + (lb == lc ? 1.f : 0.f);
        #pragma unroll
        for (int off = 8; off <= 32; off <<= 1) {
            pos_s += __shfl_xor(pos_s, off);
            neg_s += __shfl_xor(neg_s, off);
            cnt_s += __shfl_xor(cnt_s, off);
        }
        if (lane == pt) {
            const int icnt = (int)(cnt_s + 0.5f);
            if (icnt > 0 && icnt < KNBR) {
                loss_acc += -logf(pos_s / neg_s + EPSV);
                valid_acc += 1.f;
            }
        }
    }
    __shared__ float s_loss, s_cnt;
    if (threadIdx.x == 0) { s_loss = 0.f; s_cnt = 0.f; }
    __syncthreads();
    if (lane < 4) { atomicAdd(&s_loss, loss_acc); atomicAdd(&s_cnt, valid_acc); }
    __syncthreads();
    if (threadIdx.x == 0) { atomicAdd(&ws[0], s_loss); atomicAdd(&ws[1], s_cnt); }
}

__global__ void contrast_finalize(const float* __restrict__ ws,
                                  float* __restrict__ out) {
    out[0] = ws[0] / fmaxf(ws[1], 1.f) * WEIGHT;
}

extern "C" void kernel_launch(void* const* d_in, const int* in_sizes, int n_in,
                              void* d_out, int out_size, void* d_ws, size_t ws_size,
                              hipStream_t stream) {
    const float* features = (const float*)d_in[0];
    const int* labels     = (const int*)d_in[1];
    const int* nbr        = (const int*)d_in[2];
    float* out = (float*)d_out;
    float* ws  = (float*)d_ws;

    if (ws_size >= WS_NEEDED) {
        unsigned char* tbl = (unsigned char*)d_ws + TBL_OFF;
        float4* PG = (float4*)((char*)d_ws + PG_OFF);
        float* bl = (float*)((char*)d_ws + BL_OFF);
        float* bc = (float*)((char*)d_ws + BC_OFF);

        build_table<<<BLD_BLOCKS, 256, 0, stream>>>(features, labels, tbl);
        pd2_pg<<<PD_BLOCKS, 256, 0, stream>>>(tbl, nbr, PG);
        combine_loss<<<CMB_BLOCKS, 256, 0, stream>>>(PG, bl, bc);
        final_reduce<<<1, 256, 0, stream>>>(bl, bc, out);
    } else {
        (void)hipMemsetAsync(ws, 0, 16, stream);
        contrast_fp32<<<NPTS / 16, 256, 0, stream>>>(features, labels, nbr, ws);
        contrast_finalize<<<1, 1, 0, stream>>>(ws, out);
    }
}